// Round 1
// baseline (57736.511 us; speedup 1.0000x reference)
//
#include <hip/hip_runtime.h>
#include <hip/hip_cooperative_groups.h>

// Two-layer tanh RNN, persistent cooperative kernel.
// SEQ=512, B=64, IN=H=1024.
// Per step t:
//   h1 = tanh(x_t @ Wi0^T + bi0 + h1_prev @ Wh0^T + bh0)
//   h2 = tanh(h1 @ Wi1^T + bi1 + h2_prev @ Wh1^T + bh1)
// out[0:512*64*1024] = h2 per step; then h_final = [h1[511], h2[511]].
//
// Grid: 256 WGs x 256 threads. WG = (b_blk 0..15)*(n_blk 0..15):
//   tile = 4 batch rows x 64 output features, 1 output/thread.
// Weights staged in LDS per 128-wide K chunk (stride 129 -> conflict-free).
// h1/h2 double-buffered in d_ws; 2 grid syncs per step.

#define SEQ 512
#define BATCH 64
#define HID 1024

namespace cg = cooperative_groups;

__global__ __launch_bounds__(256, 1) void rnn_persistent(
    const float* __restrict__ x,
    const float* __restrict__ Wi0, const float* __restrict__ bi0,
    const float* __restrict__ Wh0, const float* __restrict__ bh0,
    const float* __restrict__ Wi1, const float* __restrict__ bi1,
    const float* __restrict__ Wh1, const float* __restrict__ bh1,
    float* __restrict__ out,
    float* __restrict__ ws)
{
    cg::grid_group grid = cg::this_grid();

    float* h1buf = ws;                       // [2][64][1024]
    float* h2buf = ws + 2 * BATCH * HID;     // [2][64][1024]

    const int tid   = threadIdx.x;
    const int wg    = blockIdx.x;
    const int n_blk = wg & 15;   // 16 blocks of 64 features
    const int b_blk = wg >> 4;   // 16 blocks of 4 batch rows
    const int n_loc = tid & 63;
    const int b_loc = tid >> 6;
    const int n = n_blk * 64 + n_loc;
    const int b = b_blk * 4 + b_loc;

    // zero-init the "prev" buffers (index 1) used at t=0
    for (int i = tid + wg * 256; i < BATCH * HID; i += 256 * 256) {
        h1buf[BATCH * HID + i] = 0.0f;
        h2buf[BATCH * HID + i] = 0.0f;
    }

    const float bias0 = bi0[n] + bh0[n];
    const float bias1 = bi1[n] + bh1[n];

    __shared__ float Wt[64][129];   // 64 features x 128 k, stride 129 (conflict-free)
    __shared__ float Xt[4][128];    // 4 batch rows x 128 k

    grid.sync();

    for (int t = 0; t < SEQ; ++t) {
        const int cur = t & 1;
        const int prv = cur ^ 1;

        // ---------------- phase A: h1 ----------------
        float acc = bias0;
        for (int half = 0; half < 2; ++half) {
            const float* W   = half ? Wh0 : Wi0;
            const float* src = half ? (h1buf + (size_t)prv * BATCH * HID)
                                    : (x + (size_t)t * BATCH * HID);
            for (int k0 = 0; k0 < HID; k0 += 128) {
                __syncthreads();
                #pragma unroll
                for (int i = 0; i < 32; ++i) {
                    int idx = tid + i * 256;
                    int row = idx >> 7, col = idx & 127;
                    Wt[row][col] = W[(size_t)(n_blk * 64 + row) * HID + k0 + col];
                }
                #pragma unroll
                for (int i = 0; i < 2; ++i) {
                    int idx = tid + i * 256;
                    int row = idx >> 7, col = idx & 127;
                    Xt[row][col] = src[(size_t)(b_blk * 4 + row) * HID + k0 + col];
                }
                __syncthreads();
                #pragma unroll 16
                for (int k = 0; k < 128; ++k)
                    acc = fmaf(Xt[b_loc][k], Wt[n_loc][k], acc);
            }
        }
        float h1v = tanhf(acc);
        h1buf[(size_t)cur * BATCH * HID + b * HID + n] = h1v;
        if (t == SEQ - 1)
            out[(size_t)SEQ * BATCH * HID + b * HID + n] = h1v;  // h_final[0]

        grid.sync();

        // ---------------- phase B: h2 ----------------
        acc = bias1;
        for (int half = 0; half < 2; ++half) {
            const float* W   = half ? Wh1 : Wi1;
            const float* src = half ? (h2buf + (size_t)prv * BATCH * HID)
                                    : (h1buf + (size_t)cur * BATCH * HID);
            for (int k0 = 0; k0 < HID; k0 += 128) {
                __syncthreads();
                #pragma unroll
                for (int i = 0; i < 32; ++i) {
                    int idx = tid + i * 256;
                    int row = idx >> 7, col = idx & 127;
                    Wt[row][col] = W[(size_t)(n_blk * 64 + row) * HID + k0 + col];
                }
                #pragma unroll
                for (int i = 0; i < 2; ++i) {
                    int idx = tid + i * 256;
                    int row = idx >> 7, col = idx & 127;
                    Xt[row][col] = src[(size_t)(b_blk * 4 + row) * HID + k0 + col];
                }
                __syncthreads();
                #pragma unroll 16
                for (int k = 0; k < 128; ++k)
                    acc = fmaf(Xt[b_loc][k], Wt[n_loc][k], acc);
            }
        }
        float h2v = tanhf(acc);
        h2buf[(size_t)cur * BATCH * HID + b * HID + n] = h2v;
        out[(size_t)t * BATCH * HID + b * HID + n] = h2v;
        if (t == SEQ - 1)
            out[(size_t)SEQ * BATCH * HID + BATCH * HID + b * HID + n] = h2v;  // h_final[1]

        grid.sync();
    }
}

extern "C" void kernel_launch(void* const* d_in, const int* in_sizes, int n_in,
                              void* d_out, int out_size, void* d_ws, size_t ws_size,
                              hipStream_t stream) {
    const float* xp   = (const float*)d_in[0];
    const float* Wi0p = (const float*)d_in[1];
    const float* bi0p = (const float*)d_in[2];
    const float* Wh0p = (const float*)d_in[3];
    const float* bh0p = (const float*)d_in[4];
    const float* Wi1p = (const float*)d_in[5];
    const float* bi1p = (const float*)d_in[6];
    const float* Wh1p = (const float*)d_in[7];
    const float* bh1p = (const float*)d_in[8];
    float* outp = (float*)d_out;
    float* wsp  = (float*)d_ws;

    void* args[] = { &xp, &Wi0p, &bi0p, &Wh0p, &bh0p,
                     &Wi1p, &bi1p, &Wh1p, &bh1p, &outp, &wsp };
    hipLaunchCooperativeKernel(reinterpret_cast<void*>(rnn_persistent),
                               dim3(256), dim3(256), args, 0, stream);
}

// Round 2
// 20157.466 us; speedup vs baseline: 2.8643x; 2.8643x over previous
//
#include <hip/hip_runtime.h>
#include <hip/hip_cooperative_groups.h>

// Two-layer tanh RNN, persistent cooperative kernel, MFMA bf16.
// h1[s] = tanh(x_s @ Wi0^T + h1[s-1] @ Wh0^T + b0)     (layer-0 WGs)
// h2[t] = tanh(h1[t] @ Wi1^T + h2[t-1] @ Wh1^T + b1)   (layer-1 WGs, t = s-1)
// Pipelined: one grid.sync per super-step (513 total).
//
// 256 WGs x 256 thr. WG = (layer, n_blk 0..63, m_blk 0..1):
//   tile = 32 batch rows x 16 features, K = 2048 (concat of two sources).
// Wave w (0..3) owns K-slice [w*512, w*512+512): weights resident in 64 VGPRs
// as bf16 B-fragments; partial C reduced across waves via LDS.
// MFMA 16x16x32 bf16 layouts:
//   A[i][k]: i = lane%16, k = 8*(lane/16)+e   (e=0..7, contiguous 16B)
//   B[k][j]: j = lane%16, k = 8*(lane/16)+e   (row of W^T = contiguous in W[n][k])
//   D[i][j]: j = lane%16, i = 4*(lane/16)+r

#define SEQ 512
#define BATCH 64
#define HID 1024

namespace cg = cooperative_groups;

typedef __attribute__((ext_vector_type(8))) short short8;
typedef __attribute__((ext_vector_type(4))) float f32x4;

__device__ __forceinline__ unsigned short f32_to_bf16_rne(float f) {
    unsigned int u = __float_as_uint(f);
    u += 0x7FFFu + ((u >> 16) & 1u);
    return (unsigned short)(u >> 16);
}

__global__ void cvt_x_bf16(const float* __restrict__ xf,
                           unsigned short* __restrict__ xb, int n4) {
    int i = blockIdx.x * blockDim.x + threadIdx.x;
    int stride = gridDim.x * blockDim.x;
    for (; i < n4; i += stride) {
        float4 f = ((const float4*)xf)[i];
        ushort4 o;
        o.x = f32_to_bf16_rne(f.x);
        o.y = f32_to_bf16_rne(f.y);
        o.z = f32_to_bf16_rne(f.z);
        o.w = f32_to_bf16_rne(f.w);
        ((ushort4*)xb)[i] = o;
    }
}

__global__ __launch_bounds__(256, 1) void rnn_mfma(
    const float* __restrict__ x,
    const unsigned short* __restrict__ xb, int use_xb,
    const float* __restrict__ Wi0, const float* __restrict__ bi0,
    const float* __restrict__ Wh0, const float* __restrict__ bh0,
    const float* __restrict__ Wi1, const float* __restrict__ bi1,
    const float* __restrict__ Wh1, const float* __restrict__ bh1,
    float* __restrict__ out,
    unsigned short* __restrict__ rings)
{
    cg::grid_group grid = cg::this_grid();

    unsigned short* h1ring = rings;                      // [2][64][1024] bf16
    unsigned short* h2ring = rings + 2 * BATCH * HID;    // [2][64][1024] bf16

    const int tid   = threadIdx.x;
    const int wg    = blockIdx.x;
    const int layer = wg >> 7;       // 0 or 1
    const int rr_   = wg & 127;
    const int n_blk = rr_ & 63;      // feature block (16 features)
    const int m_blk = rr_ >> 6;      // batch half (32 rows)
    const int wave  = tid >> 6;      // K-slice 0..3
    const int lane  = tid & 63;

    // ---- zero both rings (both slots) ----
    {
        uint4* z = (uint4*)rings;    // 4*BATCH*HID ushorts = 524288 B = 32768 uint4
        for (int i = wg * 256 + tid; i < 32768; i += 256 * 256)
            z[i] = make_uint4(0u, 0u, 0u, 0u);
    }

    // ---- load weights into registers as bf16 B-fragments ----
    const float* Wfirst  = layer ? Wi1 : Wi0;
    const float* Wsecond = layer ? Wh1 : Wh0;
    const int n_g  = n_blk * 16 + (lane & 15);
    const int kcol = (lane >> 4) * 8;

    short8 wreg[16];
    {
        const float* Wsel = (wave < 2) ? Wfirst : Wsecond;
        const float* wrow = Wsel + (size_t)n_g * HID;
        const int kbase = wave * 512 - (wave < 2 ? 0 : 1024) + kcol;
        #pragma unroll
        for (int ks = 0; ks < 16; ++ks) {
            const int k = kbase + ks * 32;
            float4 f0 = *(const float4*)(wrow + k);
            float4 f1 = *(const float4*)(wrow + k + 4);
            short8 wv;
            wv[0] = (short)f32_to_bf16_rne(f0.x);
            wv[1] = (short)f32_to_bf16_rne(f0.y);
            wv[2] = (short)f32_to_bf16_rne(f0.z);
            wv[3] = (short)f32_to_bf16_rne(f0.w);
            wv[4] = (short)f32_to_bf16_rne(f1.x);
            wv[5] = (short)f32_to_bf16_rne(f1.y);
            wv[6] = (short)f32_to_bf16_rne(f1.z);
            wv[7] = (short)f32_to_bf16_rne(f1.w);
            wreg[ks] = wv;
        }
    }

    // ---- reduce-phase constants ----
    const float* biv = layer ? bi1 : bi0;
    const float* bhv = layer ? bh1 : bh0;
    const int n_red  = n_blk * 16 + (tid & 15);
    const float biasv = biv[n_red] + bhv[n_red];

    // A-load rows for this lane
    const int row_a = lane & 15;
    const int m_g0  = m_blk * 32 + row_a;       // m-tile 0
    const int m_g1  = m_g0 + 16;                // m-tile 1

    __shared__ float red[4][32][17];            // partials, padded

    grid.sync();

    for (int s = 0; s <= SEQ; ++s) {
        const bool active = (layer == 0) ? (s < SEQ) : (s >= 1);
        f32x4 acc0 = {0.f, 0.f, 0.f, 0.f};
        f32x4 acc1 = {0.f, 0.f, 0.f, 0.f};

        if (active) {
            const int t = (layer == 0) ? s : (s - 1);
            const unsigned short* srcB16 = nullptr;
            const float* srcF32 = nullptr;
            int ko;
            if (layer == 0) {
                if (wave < 2) {
                    ko = wave * 512;
                    if (use_xb) srcB16 = xb + (size_t)t * BATCH * HID;
                    else        srcF32 = x  + (size_t)t * BATCH * HID;
                } else {
                    ko = wave * 512 - 1024;
                    srcB16 = h1ring + (size_t)((s - 1) & 1) * BATCH * HID;
                }
            } else {
                if (wave < 2) {
                    ko = wave * 512;
                    srcB16 = h1ring + (size_t)((s - 1) & 1) * BATCH * HID;
                } else {
                    ko = wave * 512 - 1024;
                    srcB16 = h2ring + (size_t)(s & 1) * BATCH * HID;
                }
            }

            if (srcB16) {
                const unsigned short* p0 = srcB16 + (size_t)m_g0 * HID + ko + kcol;
                const unsigned short* p1 = srcB16 + (size_t)m_g1 * HID + ko + kcol;
                #pragma unroll
                for (int ks = 0; ks < 16; ++ks) {
                    short8 a0 = *(const short8*)(p0 + ks * 32);
                    short8 a1 = *(const short8*)(p1 + ks * 32);
                    acc0 = __builtin_amdgcn_mfma_f32_16x16x32_bf16(a0, wreg[ks], acc0, 0, 0, 0);
                    acc1 = __builtin_amdgcn_mfma_f32_16x16x32_bf16(a1, wreg[ks], acc1, 0, 0, 0);
                }
            } else {
                const float* q0 = srcF32 + (size_t)m_g0 * HID + ko + kcol;
                const float* q1 = srcF32 + (size_t)m_g1 * HID + ko + kcol;
                #pragma unroll
                for (int ks = 0; ks < 16; ++ks) {
                    float4 f00 = *(const float4*)(q0 + ks * 32);
                    float4 f01 = *(const float4*)(q0 + ks * 32 + 4);
                    float4 f10 = *(const float4*)(q1 + ks * 32);
                    float4 f11 = *(const float4*)(q1 + ks * 32 + 4);
                    short8 a0, a1;
                    a0[0] = (short)f32_to_bf16_rne(f00.x);
                    a0[1] = (short)f32_to_bf16_rne(f00.y);
                    a0[2] = (short)f32_to_bf16_rne(f00.z);
                    a0[3] = (short)f32_to_bf16_rne(f00.w);
                    a0[4] = (short)f32_to_bf16_rne(f01.x);
                    a0[5] = (short)f32_to_bf16_rne(f01.y);
                    a0[6] = (short)f32_to_bf16_rne(f01.z);
                    a0[7] = (short)f32_to_bf16_rne(f01.w);
                    a1[0] = (short)f32_to_bf16_rne(f10.x);
                    a1[1] = (short)f32_to_bf16_rne(f10.y);
                    a1[2] = (short)f32_to_bf16_rne(f10.z);
                    a1[3] = (short)f32_to_bf16_rne(f10.w);
                    a1[4] = (short)f32_to_bf16_rne(f11.x);
                    a1[5] = (short)f32_to_bf16_rne(f11.y);
                    a1[6] = (short)f32_to_bf16_rne(f11.z);
                    a1[7] = (short)f32_to_bf16_rne(f11.w);
                    acc0 = __builtin_amdgcn_mfma_f32_16x16x32_bf16(a0, wreg[ks], acc0, 0, 0, 0);
                    acc1 = __builtin_amdgcn_mfma_f32_16x16x32_bf16(a1, wreg[ks], acc1, 0, 0, 0);
                }
            }

            // store partial C tiles to LDS: D row i = 4*(lane>>4)+r, col = lane&15
            #pragma unroll
            for (int r = 0; r < 4; ++r) {
                red[wave][(lane >> 4) * 4 + r][lane & 15]      = acc0[r];
                red[wave][16 + (lane >> 4) * 4 + r][lane & 15] = acc1[r];
            }
        }

        __syncthreads();

        if (active) {
            const int t = (layer == 0) ? s : (s - 1);
            #pragma unroll
            for (int half = 0; half < 2; ++half) {
                const int m_loc = half * 16 + (tid >> 4);
                const int nn = tid & 15;
                float v = red[0][m_loc][nn] + red[1][m_loc][nn]
                        + red[2][m_loc][nn] + red[3][m_loc][nn] + biasv;
                v = tanhf(v);
                const int m_g = m_blk * 32 + m_loc;
                const size_t oidx = (size_t)m_g * HID + n_red;
                if (layer == 0) {
                    h1ring[(size_t)(s & 1) * BATCH * HID + oidx] = f32_to_bf16_rne(v);
                    if (s == SEQ - 1)
                        out[(size_t)SEQ * BATCH * HID + oidx] = v;   // h_final[0]
                } else {
                    h2ring[(size_t)(t & 1) * BATCH * HID + oidx] = f32_to_bf16_rne(v);
                    out[(size_t)t * BATCH * HID + oidx] = v;
                    if (t == SEQ - 1)
                        out[(size_t)SEQ * BATCH * HID + BATCH * HID + oidx] = v; // h_final[1]
                }
            }
        }

        grid.sync();
    }
}

extern "C" void kernel_launch(void* const* d_in, const int* in_sizes, int n_in,
                              void* d_out, int out_size, void* d_ws, size_t ws_size,
                              hipStream_t stream) {
    const float* xp   = (const float*)d_in[0];
    const float* Wi0p = (const float*)d_in[1];
    const float* bi0p = (const float*)d_in[2];
    const float* Wh0p = (const float*)d_in[3];
    const float* bh0p = (const float*)d_in[4];
    const float* Wi1p = (const float*)d_in[5];
    const float* bi1p = (const float*)d_in[6];
    const float* Wh1p = (const float*)d_in[7];
    const float* bh1p = (const float*)d_in[8];
    float* outp = (float*)d_out;

    unsigned short* rings = (unsigned short*)d_ws;
    const size_t ring_bytes = (size_t)4 * BATCH * HID * sizeof(unsigned short); // 524288
    unsigned short* xb = (unsigned short*)((char*)d_ws + ring_bytes);
    const size_t xb_bytes = (size_t)SEQ * BATCH * HID * 2;                      // 64 MiB
    int use_xb = (ws_size >= ring_bytes + xb_bytes) ? 1 : 0;

    if (use_xb) {
        const int n4 = SEQ * BATCH * HID / 4;
        cvt_x_bf16<<<2048, 256, 0, stream>>>(xp, xb, n4);
    }

    void* args[] = { &xp, &xb, &use_xb,
                     &Wi0p, &bi0p, &Wh0p, &bh0p,
                     &Wi1p, &bi1p, &Wh1p, &bh1p,
                     &outp, &rings };
    hipLaunchCooperativeKernel(reinterpret_cast<void*>(rnn_mfma),
                               dim3(256), dim3(256), args, 0, stream);
}

// Round 3
// 14526.280 us; speedup vs baseline: 3.9746x; 1.3877x over previous
//
#include <hip/hip_runtime.h>

// Two-layer tanh RNN, persistent kernel, MFMA bf16, flag-based sync.
// h1[s] = tanh(x_s @ Wi0^T + h1[s-1] @ Wh0^T + b0)   (layer-0 WGs 0..127)
// h2[t] = tanh(h1[t] @ Wi1^T + h2[t-1] @ Wh1^T + b1) (layer-1 WGs 128..255)
//
// Sync: monotonic per-step counters c1[s], c2[t] (8 sub-counters x 16 adds).
//   layer0 @ s waits c1[s-1]==128 && c2[s-4]==128   (data + ring-WAR)
//   layer1 @ t waits c1[t]==128  && c2[t-1]==128
// Rings: 4-deep bf16 h1/h2 in ws. Weights VGPR-resident bf16 B-fragments.
// No grid.sync at all; cooperative launch only for co-residency.

#define SEQ 512
#define BATCH 64
#define HID 1024
#define NWG_L 128          // WGs per layer
#define SUBS 8             // sub-counters per step
#define SUBSTRIDE 32       // u32 stride between sub-counters (128 B)

typedef __attribute__((ext_vector_type(8))) short short8;
typedef __attribute__((ext_vector_type(4))) float f32x4;

__device__ __forceinline__ unsigned short f32_to_bf16_rne(float f) {
    unsigned int u = __float_as_uint(f);
    u += 0x7FFFu + ((u >> 16) & 1u);
    return (unsigned short)(u >> 16);
}

__global__ void cvt_x_bf16(const float* __restrict__ xf,
                           unsigned short* __restrict__ xb, int n4) {
    int i = blockIdx.x * blockDim.x + threadIdx.x;
    int stride = gridDim.x * blockDim.x;
    for (; i < n4; i += stride) {
        float4 f = ((const float4*)xf)[i];
        ushort4 o;
        o.x = f32_to_bf16_rne(f.x);
        o.y = f32_to_bf16_rne(f.y);
        o.z = f32_to_bf16_rne(f.z);
        o.w = f32_to_bf16_rne(f.w);
        ((ushort4*)xb)[i] = o;
    }
}

// zero rings (1 MB) + flags (1 MB) at the head of ws
__global__ void init_ws(uint4* __restrict__ p, int n16) {
    int i = blockIdx.x * blockDim.x + threadIdx.x;
    if (i < n16) p[i] = make_uint4(0u, 0u, 0u, 0u);
}

__device__ __forceinline__ void wait_cnt(unsigned int* base, unsigned target) {
    for (;;) {
        unsigned s = 0;
        #pragma unroll
        for (int j = 0; j < SUBS; ++j)
            s += __hip_atomic_load(base + j * SUBSTRIDE,
                                   __ATOMIC_RELAXED, __HIP_MEMORY_SCOPE_AGENT);
        if (s >= target) return;
        __builtin_amdgcn_s_sleep(2);
    }
}

__global__ __launch_bounds__(256, 1) void rnn_mfma(
    const float* __restrict__ x,
    const unsigned short* __restrict__ xb, int use_xb,
    const float* __restrict__ Wi0, const float* __restrict__ bi0,
    const float* __restrict__ Wh0, const float* __restrict__ bh0,
    const float* __restrict__ Wi1, const float* __restrict__ bi1,
    const float* __restrict__ Wh1, const float* __restrict__ bh1,
    float* __restrict__ out,
    unsigned short* __restrict__ rings,
    unsigned int* __restrict__ flags)
{
    // rings: h1[4][64][1024] bf16, then h2[4][64][1024] bf16
    unsigned short* h1ring = rings;
    unsigned short* h2ring = rings + 4 * BATCH * HID;
    unsigned int* c1 = flags;                          // [SEQ][SUBS*SUBSTRIDE]
    unsigned int* c2 = flags + SEQ * SUBS * SUBSTRIDE;

    const int tid   = threadIdx.x;
    const int wg    = blockIdx.x;
    const int layer = wg >> 7;       // 0 or 1
    const int rr_   = wg & 127;
    const int n_blk = rr_ & 63;      // feature block (16 features)
    const int m_blk = rr_ >> 6;      // batch half (32 rows)
    const int wave  = tid >> 6;      // K-slice 0..3
    const int lane  = tid & 63;

    // ---- load weights into registers as bf16 B-fragments ----
    const float* Wfirst  = layer ? Wi1 : Wi0;
    const float* Wsecond = layer ? Wh1 : Wh0;
    const int n_g  = n_blk * 16 + (lane & 15);
    const int kcol = (lane >> 4) * 8;

    short8 wreg[16];
    {
        const float* Wsel = (wave < 2) ? Wfirst : Wsecond;
        const float* wrow = Wsel + (size_t)n_g * HID;
        const int kbase = (wave & 1) * 512 + kcol;
        #pragma unroll
        for (int ks = 0; ks < 16; ++ks) {
            const int k = kbase + ks * 32;
            float4 f0 = *(const float4*)(wrow + k);
            float4 f1 = *(const float4*)(wrow + k + 4);
            short8 wv;
            wv[0] = (short)f32_to_bf16_rne(f0.x);
            wv[1] = (short)f32_to_bf16_rne(f0.y);
            wv[2] = (short)f32_to_bf16_rne(f0.z);
            wv[3] = (short)f32_to_bf16_rne(f0.w);
            wv[4] = (short)f32_to_bf16_rne(f1.x);
            wv[5] = (short)f32_to_bf16_rne(f1.y);
            wv[6] = (short)f32_to_bf16_rne(f1.z);
            wv[7] = (short)f32_to_bf16_rne(f1.w);
            wreg[ks] = wv;
        }
    }

    const float* biv = layer ? bi1 : bi0;
    const float* bhv = layer ? bh1 : bh0;
    const int n_red  = n_blk * 16 + (tid & 15);
    const float biasv = biv[n_red] + bhv[n_red];

    const int m_g0 = m_blk * 32 + (lane & 15);   // A row, m-tile 0
    const int m_g1 = m_g0 + 16;                  // A row, m-tile 1

    __shared__ float red[4][32][17];

    unsigned int* mycnt  = layer ? c2 : c1;
    unsigned int* othcnt = layer ? c1 : c2;

    for (int s = 0; s < SEQ; ++s) {
        // ---------- wait ----------
        if (tid == 0) {
            if (layer == 0) {
                if (s >= 1) wait_cnt(c1 + (s - 1) * SUBS * SUBSTRIDE, NWG_L);
                if (s >= 4) wait_cnt(c2 + (s - 4) * SUBS * SUBSTRIDE, NWG_L);
            } else {
                wait_cnt(c1 + s * SUBS * SUBSTRIDE, NWG_L);
                if (s >= 1) wait_cnt(c2 + (s - 1) * SUBS * SUBSTRIDE, NWG_L);
            }
        }
        __syncthreads();
        __builtin_amdgcn_fence(__ATOMIC_ACQUIRE, "agent");

        // ---------- compute ----------
        f32x4 acc0 = {0.f, 0.f, 0.f, 0.f};
        f32x4 acc1 = {0.f, 0.f, 0.f, 0.f};

        const unsigned short* srcB16 = nullptr;
        const float* srcF32 = nullptr;
        const int ko = (wave & 1) * 512;
        if (layer == 0) {
            if (wave < 2) {
                if (use_xb) srcB16 = xb + (size_t)s * BATCH * HID;
                else        srcF32 = x  + (size_t)s * BATCH * HID;
            } else {
                srcB16 = h1ring + (size_t)((s - 1) & 3) * BATCH * HID;
            }
        } else {
            if (wave < 2) srcB16 = h1ring + (size_t)(s & 3) * BATCH * HID;
            else          srcB16 = h2ring + (size_t)((s - 1) & 3) * BATCH * HID;
        }

        if (srcB16) {
            const unsigned short* p0 = srcB16 + (size_t)m_g0 * HID + ko + kcol;
            const unsigned short* p1 = srcB16 + (size_t)m_g1 * HID + ko + kcol;
            #pragma unroll
            for (int ks = 0; ks < 16; ++ks) {
                short8 a0 = *(const short8*)(p0 + ks * 32);
                short8 a1 = *(const short8*)(p1 + ks * 32);
                acc0 = __builtin_amdgcn_mfma_f32_16x16x32_bf16(a0, wreg[ks], acc0, 0, 0, 0);
                acc1 = __builtin_amdgcn_mfma_f32_16x16x32_bf16(a1, wreg[ks], acc1, 0, 0, 0);
            }
        } else {
            const float* q0 = srcF32 + (size_t)m_g0 * HID + ko + kcol;
            const float* q1 = srcF32 + (size_t)m_g1 * HID + ko + kcol;
            #pragma unroll
            for (int ks = 0; ks < 16; ++ks) {
                float4 f00 = *(const float4*)(q0 + ks * 32);
                float4 f01 = *(const float4*)(q0 + ks * 32 + 4);
                float4 f10 = *(const float4*)(q1 + ks * 32);
                float4 f11 = *(const float4*)(q1 + ks * 32 + 4);
                short8 a0, a1;
                a0[0] = (short)f32_to_bf16_rne(f00.x);
                a0[1] = (short)f32_to_bf16_rne(f00.y);
                a0[2] = (short)f32_to_bf16_rne(f00.z);
                a0[3] = (short)f32_to_bf16_rne(f00.w);
                a0[4] = (short)f32_to_bf16_rne(f01.x);
                a0[5] = (short)f32_to_bf16_rne(f01.y);
                a0[6] = (short)f32_to_bf16_rne(f01.z);
                a0[7] = (short)f32_to_bf16_rne(f01.w);
                a1[0] = (short)f32_to_bf16_rne(f10.x);
                a1[1] = (short)f32_to_bf16_rne(f10.y);
                a1[2] = (short)f32_to_bf16_rne(f10.z);
                a1[3] = (short)f32_to_bf16_rne(f10.w);
                a1[4] = (short)f32_to_bf16_rne(f11.x);
                a1[5] = (short)f32_to_bf16_rne(f11.y);
                a1[6] = (short)f32_to_bf16_rne(f11.z);
                a1[7] = (short)f32_to_bf16_rne(f11.w);
                acc0 = __builtin_amdgcn_mfma_f32_16x16x32_bf16(a0, wreg[ks], acc0, 0, 0, 0);
                acc1 = __builtin_amdgcn_mfma_f32_16x16x32_bf16(a1, wreg[ks], acc1, 0, 0, 0);
            }
        }

        // partial C tiles to LDS: D row i = 4*(lane>>4)+r, col = lane&15
        #pragma unroll
        for (int r = 0; r < 4; ++r) {
            red[wave][(lane >> 4) * 4 + r][lane & 15]      = acc0[r];
            red[wave][16 + (lane >> 4) * 4 + r][lane & 15] = acc1[r];
        }

        __syncthreads();

        // ---------- reduce + activation + stores ----------
        #pragma unroll
        for (int half = 0; half < 2; ++half) {
            const int m_loc = half * 16 + (tid >> 4);
            const int nn = tid & 15;
            float v = red[0][m_loc][nn] + red[1][m_loc][nn]
                    + red[2][m_loc][nn] + red[3][m_loc][nn] + biasv;
            v = tanhf(v);
            const int m_g = m_blk * 32 + m_loc;
            const size_t oidx = (size_t)m_g * HID + n_red;
            if (layer == 0) {
                h1ring[(size_t)(s & 3) * BATCH * HID + oidx] = f32_to_bf16_rne(v);
                if (s == SEQ - 1)
                    out[(size_t)SEQ * BATCH * HID + oidx] = v;           // h_final[0]
            } else {
                h2ring[(size_t)(s & 3) * BATCH * HID + oidx] = f32_to_bf16_rne(v);
                out[(size_t)s * BATCH * HID + oidx] = v;
                if (s == SEQ - 1)
                    out[(size_t)SEQ * BATCH * HID + BATCH * HID + oidx] = v; // h_final[1]
            }
        }

        // ---------- signal ----------
        __builtin_amdgcn_fence(__ATOMIC_RELEASE, "agent");
        __syncthreads();
        if (tid == 0)
            __hip_atomic_fetch_add(mycnt + s * SUBS * SUBSTRIDE + (wg & 7) * SUBSTRIDE,
                                   1u, __ATOMIC_RELAXED, __HIP_MEMORY_SCOPE_AGENT);
        (void)othcnt;
    }
}

extern "C" void kernel_launch(void* const* d_in, const int* in_sizes, int n_in,
                              void* d_out, int out_size, void* d_ws, size_t ws_size,
                              hipStream_t stream) {
    const float* xp   = (const float*)d_in[0];
    const float* Wi0p = (const float*)d_in[1];
    const float* bi0p = (const float*)d_in[2];
    const float* Wh0p = (const float*)d_in[3];
    const float* bh0p = (const float*)d_in[4];
    const float* Wi1p = (const float*)d_in[5];
    const float* bi1p = (const float*)d_in[6];
    const float* Wh1p = (const float*)d_in[7];
    const float* bh1p = (const float*)d_in[8];
    float* outp = (float*)d_out;

    // ws layout: rings (1 MB) | flags (1 MB) | xb (64 MB)
    unsigned short* rings = (unsigned short*)d_ws;
    const size_t ring_bytes = (size_t)8 * BATCH * HID * sizeof(unsigned short); // 1 MiB
    unsigned int* flags = (unsigned int*)((char*)d_ws + ring_bytes);
    const size_t flag_bytes = (size_t)2 * SEQ * SUBS * SUBSTRIDE * 4;           // 1 MiB
    unsigned short* xb = (unsigned short*)((char*)d_ws + ring_bytes + flag_bytes);
    const size_t xb_bytes = (size_t)SEQ * BATCH * HID * 2;                      // 64 MiB
    int use_xb = (ws_size >= ring_bytes + flag_bytes + xb_bytes) ? 1 : 0;

    // zero rings + flags (2 MB = 131072 uint4)
    {
        const int n16 = (int)((ring_bytes + flag_bytes) / 16);
        init_ws<<<(n16 + 255) / 256, 256, 0, stream>>>((uint4*)d_ws, n16);
    }
    if (use_xb) {
        const int n4 = SEQ * BATCH * HID / 4;
        cvt_x_bf16<<<2048, 256, 0, stream>>>(xp, xb, n4);
    }

    void* args[] = { &xp, &xb, &use_xb,
                     &Wi0p, &bi0p, &Wh0p, &bh0p,
                     &Wi1p, &bi1p, &Wh1p, &bh1p,
                     &outp, &rings, &flags };
    hipLaunchCooperativeKernel(reinterpret_cast<void*>(rnn_mfma),
                               dim3(256), dim3(256), args, 0, stream);
}

// Round 4
// 5360.825 us; speedup vs baseline: 10.7701x; 2.7097x over previous
//
#include <hip/hip_runtime.h>

// Two-layer tanh RNN, persistent kernel, MFMA bf16, fence-free atomic rings.
// h1[s] = tanh(x_s @ Wi0^T + h1[s-1] @ Wh0^T + b0)   (layer-0 WGs 0..127)
// h2[t] = tanh(h1[t] @ Wi1^T + h2[t-1] @ Wh1^T + b1) (layer-1 WGs 128..255)
//
// Sync: monotonic per-step counters (8 sub-counters); NO bulk fences.
// All ring data moves via relaxed AGENT-scope atomics (8B granules) which are
// coherent at the device coherence point; store->flag ordering via
// s_waitcnt vmcnt(0) + __syncthreads before the flag add.
// Weights VGPR-resident bf16 B-fragments. Rings 4-deep.

#define SEQ 512
#define BATCH 64
#define HID 1024
#define NWG_L 128
#define SUBS 8
#define SUBSTRIDE 32
#define BH (BATCH * HID)

typedef __attribute__((ext_vector_type(8))) short short8;
typedef __attribute__((ext_vector_type(4))) float f32x4;

struct Q2 { unsigned long long lo, hi; };

__device__ __forceinline__ unsigned short f32_to_bf16_rne(float f) {
    unsigned int u = __float_as_uint(f);
    u += 0x7FFFu + ((u >> 16) & 1u);
    return (unsigned short)(u >> 16);
}

__device__ __forceinline__ short8 ld_ring16(const unsigned short* p) {
    Q2 q;
    q.lo = __hip_atomic_load((const unsigned long long*)p,
                             __ATOMIC_RELAXED, __HIP_MEMORY_SCOPE_AGENT);
    q.hi = __hip_atomic_load(((const unsigned long long*)p) + 1,
                             __ATOMIC_RELAXED, __HIP_MEMORY_SCOPE_AGENT);
    return __builtin_bit_cast(short8, q);
}

__device__ __forceinline__ unsigned long long pack4_bf16(float a, float b, float c, float d) {
    return (unsigned long long)f32_to_bf16_rne(a)
         | ((unsigned long long)f32_to_bf16_rne(b) << 16)
         | ((unsigned long long)f32_to_bf16_rne(c) << 32)
         | ((unsigned long long)f32_to_bf16_rne(d) << 48);
}

__global__ void cvt_x_bf16(const float* __restrict__ xf,
                           unsigned short* __restrict__ xb, int n4) {
    int i = blockIdx.x * blockDim.x + threadIdx.x;
    int stride = gridDim.x * blockDim.x;
    for (; i < n4; i += stride) {
        float4 f = ((const float4*)xf)[i];
        ushort4 o;
        o.x = f32_to_bf16_rne(f.x);
        o.y = f32_to_bf16_rne(f.y);
        o.z = f32_to_bf16_rne(f.z);
        o.w = f32_to_bf16_rne(f.w);
        ((ushort4*)xb)[i] = o;
    }
}

__global__ void init_ws(uint4* __restrict__ p, int n16) {
    int i = blockIdx.x * blockDim.x + threadIdx.x;
    if (i < n16) p[i] = make_uint4(0u, 0u, 0u, 0u);
}

__device__ __forceinline__ void wait_cnt(unsigned int* base, unsigned target) {
    for (;;) {
        unsigned s = 0;
        #pragma unroll
        for (int j = 0; j < SUBS; ++j)
            s += __hip_atomic_load(base + j * SUBSTRIDE,
                                   __ATOMIC_RELAXED, __HIP_MEMORY_SCOPE_AGENT);
        if (s >= target) return;
        __builtin_amdgcn_s_sleep(2);
    }
}

__global__ __launch_bounds__(256, 1) void rnn_mfma(
    const float* __restrict__ x,
    const unsigned short* __restrict__ xb, int use_xb,
    const float* __restrict__ Wi0, const float* __restrict__ bi0,
    const float* __restrict__ Wh0, const float* __restrict__ bh0,
    const float* __restrict__ Wi1, const float* __restrict__ bi1,
    const float* __restrict__ Wh1, const float* __restrict__ bh1,
    float* __restrict__ out,
    unsigned short* __restrict__ rings,
    unsigned int* __restrict__ flags)
{
    unsigned short* h1ring = rings;              // [4][64][1024] bf16
    unsigned short* h2ring = rings + 4 * BH;     // [4][64][1024] bf16
    unsigned int* c1 = flags;                    // [SEQ][SUBS*SUBSTRIDE]
    unsigned int* c2 = flags + SEQ * SUBS * SUBSTRIDE;

    const int tid   = threadIdx.x;
    const int wg    = blockIdx.x;
    const int layer = wg >> 7;
    const int rr_   = wg & 127;
    const int n_blk = rr_ & 63;      // 16-feature block
    const int m_blk = rr_ >> 6;      // 32-row batch half
    const int wave  = tid >> 6;
    const int lane  = tid & 63;

    // ---- weights -> VGPR bf16 B-fragments ----
    const float* Wfirst  = layer ? Wi1 : Wi0;
    const float* Wsecond = layer ? Wh1 : Wh0;
    const int n_g  = n_blk * 16 + (lane & 15);
    const int kcol = (lane >> 4) * 8;

    short8 wreg[16];
    {
        const float* Wsel = (wave < 2) ? Wfirst : Wsecond;
        const float* wrow = Wsel + (size_t)n_g * HID;
        const int kbase = (wave & 1) * 512 + kcol;
        #pragma unroll
        for (int ks = 0; ks < 16; ++ks) {
            const int k = kbase + ks * 32;
            float4 f0 = *(const float4*)(wrow + k);
            float4 f1 = *(const float4*)(wrow + k + 4);
            short8 wv;
            wv[0] = (short)f32_to_bf16_rne(f0.x);
            wv[1] = (short)f32_to_bf16_rne(f0.y);
            wv[2] = (short)f32_to_bf16_rne(f0.z);
            wv[3] = (short)f32_to_bf16_rne(f0.w);
            wv[4] = (short)f32_to_bf16_rne(f1.x);
            wv[5] = (short)f32_to_bf16_rne(f1.y);
            wv[6] = (short)f32_to_bf16_rne(f1.z);
            wv[7] = (short)f32_to_bf16_rne(f1.w);
            wreg[ks] = wv;
        }
    }

    // ---- reduce-phase constants (tid<128 does 1 row x 4 features) ----
    const float* biv = layer ? bi1 : bi0;
    const float* bhv = layer ? bh1 : bh0;
    const int r_row = tid >> 2;            // 0..31 (for tid<128)
    const int r_cg  = tid & 3;             // 0..3
    const int n_b   = n_blk * 16 + r_cg * 4;
    float bias4[4];
    #pragma unroll
    for (int j = 0; j < 4; ++j) bias4[j] = biv[n_b + j] + bhv[n_b + j];

    const int m_g0 = m_blk * 32 + (lane & 15);   // A row, m-tile 0
    const int m_g1 = m_g0 + 16;                  // A row, m-tile 1

    __shared__ float red[4][32][17];

    unsigned int* mycnt = layer ? c2 : c1;

    for (int s = 0; s < SEQ; ++s) {
        // ---------- wait (tid 0 polls, no fence after) ----------
        if (tid == 0) {
            if (layer == 0) {
                if (s >= 1) wait_cnt(c1 + (s - 1) * SUBS * SUBSTRIDE, NWG_L);
                if (s >= 4) wait_cnt(c2 + (s - 4) * SUBS * SUBSTRIDE, NWG_L);
            } else {
                wait_cnt(c1 + s * SUBS * SUBSTRIDE, NWG_L);
                if (s >= 1) wait_cnt(c2 + (s - 1) * SUBS * SUBSTRIDE, NWG_L);
            }
        }
        __syncthreads();

        // ---------- compute ----------
        f32x4 acc0 = {0.f, 0.f, 0.f, 0.f};
        f32x4 acc1 = {0.f, 0.f, 0.f, 0.f};

        const unsigned short* ringsrc = nullptr;
        const int ko = (wave & 1) * 512;
        if (layer == 0) {
            if (wave >= 2) ringsrc = h1ring + (size_t)((s - 1) & 3) * BH;
        } else {
            ringsrc = (wave < 2) ? (h1ring + (size_t)(s & 3) * BH)
                                 : (h2ring + (size_t)((s - 1) & 3) * BH);
        }

        if (ringsrc) {
            const unsigned short* p0 = ringsrc + (size_t)m_g0 * HID + ko + kcol;
            const unsigned short* p1 = ringsrc + (size_t)m_g1 * HID + ko + kcol;
            #pragma unroll
            for (int ks = 0; ks < 16; ++ks) {
                short8 a0 = ld_ring16(p0 + ks * 32);
                short8 a1 = ld_ring16(p1 + ks * 32);
                acc0 = __builtin_amdgcn_mfma_f32_16x16x32_bf16(a0, wreg[ks], acc0, 0, 0, 0);
                acc1 = __builtin_amdgcn_mfma_f32_16x16x32_bf16(a1, wreg[ks], acc1, 0, 0, 0);
            }
        } else if (use_xb) {
            const unsigned short* p0 = xb + (size_t)s * BH + (size_t)m_g0 * HID + ko + kcol;
            const unsigned short* p1 = xb + (size_t)s * BH + (size_t)m_g1 * HID + ko + kcol;
            #pragma unroll
            for (int ks = 0; ks < 16; ++ks) {
                short8 a0 = *(const short8*)(p0 + ks * 32);
                short8 a1 = *(const short8*)(p1 + ks * 32);
                acc0 = __builtin_amdgcn_mfma_f32_16x16x32_bf16(a0, wreg[ks], acc0, 0, 0, 0);
                acc1 = __builtin_amdgcn_mfma_f32_16x16x32_bf16(a1, wreg[ks], acc1, 0, 0, 0);
            }
        } else {
            const float* q0 = x + (size_t)s * BH + (size_t)m_g0 * HID + ko + kcol;
            const float* q1 = x + (size_t)s * BH + (size_t)m_g1 * HID + ko + kcol;
            #pragma unroll
            for (int ks = 0; ks < 16; ++ks) {
                float4 f00 = *(const float4*)(q0 + ks * 32);
                float4 f01 = *(const float4*)(q0 + ks * 32 + 4);
                float4 f10 = *(const float4*)(q1 + ks * 32);
                float4 f11 = *(const float4*)(q1 + ks * 32 + 4);
                short8 a0, a1;
                a0[0] = (short)f32_to_bf16_rne(f00.x);
                a0[1] = (short)f32_to_bf16_rne(f00.y);
                a0[2] = (short)f32_to_bf16_rne(f00.z);
                a0[3] = (short)f32_to_bf16_rne(f00.w);
                a0[4] = (short)f32_to_bf16_rne(f01.x);
                a0[5] = (short)f32_to_bf16_rne(f01.y);
                a0[6] = (short)f32_to_bf16_rne(f01.z);
                a0[7] = (short)f32_to_bf16_rne(f01.w);
                a1[0] = (short)f32_to_bf16_rne(f10.x);
                a1[1] = (short)f32_to_bf16_rne(f10.y);
                a1[2] = (short)f32_to_bf16_rne(f10.z);
                a1[3] = (short)f32_to_bf16_rne(f10.w);
                a1[4] = (short)f32_to_bf16_rne(f11.x);
                a1[5] = (short)f32_to_bf16_rne(f11.y);
                a1[6] = (short)f32_to_bf16_rne(f11.z);
                a1[7] = (short)f32_to_bf16_rne(f11.w);
                acc0 = __builtin_amdgcn_mfma_f32_16x16x32_bf16(a0, wreg[ks], acc0, 0, 0, 0);
                acc1 = __builtin_amdgcn_mfma_f32_16x16x32_bf16(a1, wreg[ks], acc1, 0, 0, 0);
            }
        }

        // partial C tiles to LDS: D row i = 4*(lane>>4)+r, col = lane&15
        #pragma unroll
        for (int r = 0; r < 4; ++r) {
            red[wave][(lane >> 4) * 4 + r][lane & 15]      = acc0[r];
            red[wave][16 + (lane >> 4) * 4 + r][lane & 15] = acc1[r];
        }

        __syncthreads();

        // ---------- reduce + tanh + stores (tid<128: one row x 4 feats) ----------
        if (tid < 128) {
            const int m_g = m_blk * 32 + r_row;
            float v[4];
            #pragma unroll
            for (int j = 0; j < 4; ++j) {
                const int c = r_cg * 4 + j;
                float sacc = red[0][r_row][c] + red[1][r_row][c]
                           + red[2][r_row][c] + red[3][r_row][c] + bias4[j];
                v[j] = tanhf(sacc);
            }
            const unsigned long long pk = pack4_bf16(v[0], v[1], v[2], v[3]);
            const size_t oidx = (size_t)m_g * HID + n_b;
            if (layer == 0) {
                __hip_atomic_store((unsigned long long*)(h1ring + (size_t)(s & 3) * BH + oidx),
                                   pk, __ATOMIC_RELAXED, __HIP_MEMORY_SCOPE_AGENT);
                if (s == SEQ - 1)
                    *(float4*)(out + (size_t)SEQ * BH + oidx) =
                        make_float4(v[0], v[1], v[2], v[3]);            // h_final[0]
            } else {
                __hip_atomic_store((unsigned long long*)(h2ring + (size_t)(s & 3) * BH + oidx),
                                   pk, __ATOMIC_RELAXED, __HIP_MEMORY_SCOPE_AGENT);
                *(float4*)(out + (size_t)s * BH + oidx) =
                    make_float4(v[0], v[1], v[2], v[3]);
                if (s == SEQ - 1)
                    *(float4*)(out + (size_t)SEQ * BH + BH + oidx) =
                        make_float4(v[0], v[1], v[2], v[3]);            // h_final[1]
            }
        }

        // ---------- signal: ack stores, then one add ----------
        asm volatile("s_waitcnt vmcnt(0)" ::: "memory");
        __syncthreads();
        if (tid == 0)
            __hip_atomic_fetch_add(mycnt + s * SUBS * SUBSTRIDE + (wg & 7) * SUBSTRIDE,
                                   1u, __ATOMIC_RELAXED, __HIP_MEMORY_SCOPE_AGENT);
    }
}

extern "C" void kernel_launch(void* const* d_in, const int* in_sizes, int n_in,
                              void* d_out, int out_size, void* d_ws, size_t ws_size,
                              hipStream_t stream) {
    const float* xp   = (const float*)d_in[0];
    const float* Wi0p = (const float*)d_in[1];
    const float* bi0p = (const float*)d_in[2];
    const float* Wh0p = (const float*)d_in[3];
    const float* bh0p = (const float*)d_in[4];
    const float* Wi1p = (const float*)d_in[5];
    const float* bi1p = (const float*)d_in[6];
    const float* Wh1p = (const float*)d_in[7];
    const float* bh1p = (const float*)d_in[8];
    float* outp = (float*)d_out;

    // ws layout: rings (1 MB) | flags (1 MB) | xb (64 MB)
    unsigned short* rings = (unsigned short*)d_ws;
    const size_t ring_bytes = (size_t)8 * BH * sizeof(unsigned short);
    unsigned int* flags = (unsigned int*)((char*)d_ws + ring_bytes);
    const size_t flag_bytes = (size_t)2 * SEQ * SUBS * SUBSTRIDE * 4;
    unsigned short* xb = (unsigned short*)((char*)d_ws + ring_bytes + flag_bytes);
    const size_t xb_bytes = (size_t)SEQ * BH * 2;
    int use_xb = (ws_size >= ring_bytes + flag_bytes + xb_bytes) ? 1 : 0;

    {
        const int n16 = (int)((ring_bytes + flag_bytes) / 16);
        init_ws<<<(n16 + 255) / 256, 256, 0, stream>>>((uint4*)d_ws, n16);
    }
    if (use_xb) {
        const int n4 = SEQ * BH / 4;
        cvt_x_bf16<<<2048, 256, 0, stream>>>(xp, xb, n4);
    }

    void* args[] = { &xp, &xb, &use_xb,
                     &Wi0p, &bi0p, &Wh0p, &bh0p,
                     &Wi1p, &bi1p, &Wh1p, &bh1p,
                     &outp, &rings, &flags };
    hipLaunchCooperativeKernel(reinterpret_cast<void*>(rnn_mfma),
                               dim3(256), dim3(256), args, 0, stream);
}